// Round 6
// baseline (349.712 us; speedup 1.0000x reference)
//
#include <hip/hip_runtime.h>
#include <math.h>

// Problem constants (from reference setup_inputs)
#define T_TOKENS 16384
#define DIM      2048
#define NEXP     64
#define TOPK     2

#define KB    1024             // K per block (split-K x2: kc = blockIdx & 1)
#define SK    128              // k's per LDS stage
#define NST   (KB / SK)        // 8 stages
#define XTS   65               // transposed x stride (64 rows + 1, ODD => conflict-free column reads)
#define PS    68               // partial-tile row stride

// Flat fp32 output layout: combine | topk_idx | gates | expert_activation
#define OFF_COMBINE 0
#define OFF_IDX     (T_TOKENS * NEXP)
#define OFF_GATES   (OFF_IDX + T_TOKENS * TOPK)
#define OFF_ACT     (OFF_GATES + T_TOKENS * TOPK)

// Union LDS: x-stage (2*128*65 = 16640 fl) and partial tile (4*64*68 = 17408 fl)
#define SMEM_FLOATS 17408

__device__ __forceinline__ void fma16(float* acc, float xs, const float* __restrict__ wk) {
    const float4 w0 = *reinterpret_cast<const float4*>(wk);
    const float4 w1 = *reinterpret_cast<const float4*>(wk + 4);
    const float4 w2 = *reinterpret_cast<const float4*>(wk + 8);
    const float4 w3 = *reinterpret_cast<const float4*>(wk + 12);
    acc[0]  = fmaf(xs, w0.x, acc[0]);  acc[1]  = fmaf(xs, w0.y, acc[1]);
    acc[2]  = fmaf(xs, w0.z, acc[2]);  acc[3]  = fmaf(xs, w0.w, acc[3]);
    acc[4]  = fmaf(xs, w1.x, acc[4]);  acc[5]  = fmaf(xs, w1.y, acc[5]);
    acc[6]  = fmaf(xs, w1.z, acc[6]);  acc[7]  = fmaf(xs, w1.w, acc[7]);
    acc[8]  = fmaf(xs, w2.x, acc[8]);  acc[9]  = fmaf(xs, w2.y, acc[9]);
    acc[10] = fmaf(xs, w2.z, acc[10]); acc[11] = fmaf(xs, w2.w, acc[11]);
    acc[12] = fmaf(xs, w3.x, acc[12]); acc[13] = fmaf(xs, w3.y, acc[13]);
    acc[14] = fmaf(xs, w3.z, acc[14]); acc[15] = fmaf(xs, w3.w, acc[15]);
}

// K1: split-K GEMM with an SMEM-free K-loop.
//  - w: uniform-address global_load (vmcnt path; ds_bpermute taint blocks s_load promotion)
//  - x: staged to LDS transposed [k][row], odd stride -> conflict-free ds_read_b32
// Grid 512 (tile = bx>>1, kc = bx&1), 1024 thr = 16 waves = 4 eg x 4 sub, acc16/lane.
__global__ __launch_bounds__(1024, 8)
void gemm_kernel(const float* __restrict__ x,
                 const float* __restrict__ w,     // [DIM][NEXP]
                 float* __restrict__ out,         // kc=0 partial -> combine region
                 float* __restrict__ p1) {        // kc=1 partial -> ws (4 MB)
    __shared__ float smem[SMEM_FLOATS];          // 69632 B -> 2 blocks/CU

    const int tid  = threadIdx.x;
    const int lane = tid & 63;
    const int wv   = __builtin_amdgcn_readfirstlane(tid >> 6);
    const int eg   = wv & 3;        // expert group: experts [eg*16, eg*16+16)
    const int sub  = wv >> 2;       // 32-k quarter of each 128-k stage
    const int tile = blockIdx.x >> 1;
    const int kc   = blockIdx.x & 1;
    const int k0   = kc * KB;

    if (blockIdx.x == 0 && tid < NEXP) out[OFF_ACT + tid] = 0.0f;

    // Opaque per-lane zero: keeps w addresses "divergent" so loads stay on VMEM.
    const int vz = __builtin_amdgcn_ds_bpermute(0, 0);
    const float* __restrict__ wbase = w + vz + (size_t)k0 * NEXP + eg * 16;

    // Staging mapping: row sr (64), k-segment skk (16 segs x 8 floats = 128 k).
    const int sr  = tid >> 4;
    const int skk = (tid & 15) * 8;
    const float* __restrict__ xg = x + (size_t)(tile * 64 + sr) * DIM + k0 + skk;

    float acc[16];
    #pragma unroll
    for (int i = 0; i < 16; ++i) acc[i] = 0.0f;

    // Prologue: stage 0 -> transposed LDS.
    {
        const float4 pa = *reinterpret_cast<const float4*>(xg);
        const float4 pb = *reinterpret_cast<const float4*>(xg + 4);
        float* bp = smem + skk * XTS + sr;
        bp[0 * XTS] = pa.x; bp[1 * XTS] = pa.y; bp[2 * XTS] = pa.z; bp[3 * XTS] = pa.w;
        bp[4 * XTS] = pb.x; bp[5 * XTS] = pb.y; bp[6 * XTS] = pb.z; bp[7 * XTS] = pb.w;
    }
    __syncthreads();

    #pragma unroll 1
    for (int s = 0; s < NST; ++s) {
        const int buf = s & 1;
        // Next-stage global prefetch, issued before the compute body (vmcnt).
        float4 na = make_float4(0.f, 0.f, 0.f, 0.f), nb = na;
        const bool more = (s + 1 < NST);
        if (more) {
            na = *reinterpret_cast<const float4*>(xg + (s + 1) * SK);
            nb = *reinterpret_cast<const float4*>(xg + (s + 1) * SK + 4);
        }

        const float* xls = smem + buf * (SK * XTS) + (sub * 32) * XTS + lane;
        const float* wr  = wbase + (size_t)(s * SK + sub * 32) * NEXP;

        #pragma unroll
        for (int kk = 0; kk < 32; kk += 4) {
            const float x0 = xls[(kk + 0) * XTS];
            const float x1 = xls[(kk + 1) * XTS];
            const float x2 = xls[(kk + 2) * XTS];
            const float x3 = xls[(kk + 3) * XTS];
            const float* wk = wr + (size_t)kk * NEXP;
            fma16(acc, x0, wk);
            fma16(acc, x1, wk + NEXP);
            fma16(acc, x2, wk + 2 * NEXP);
            fma16(acc, x3, wk + 3 * NEXP);
        }

        if (more) {
            float* bp = smem + (buf ^ 1) * (SK * XTS) + skk * XTS + sr;
            bp[0 * XTS] = na.x; bp[1 * XTS] = na.y; bp[2 * XTS] = na.z; bp[3 * XTS] = na.w;
            bp[4 * XTS] = nb.x; bp[5 * XTS] = nb.y; bp[6 * XTS] = nb.z; bp[7 * XTS] = nb.w;
        }
        __syncthreads();   // also the safety barrier before smem reuse after last stage
    }

    // Reuse smem as the partial tile: part[sub][row][e], stride PS.
    {
        float* pr = smem + sub * (64 * PS) + lane * PS + eg * 16;
        *reinterpret_cast<float4*>(pr + 0)  = make_float4(acc[0],  acc[1],  acc[2],  acc[3]);
        *reinterpret_cast<float4*>(pr + 4)  = make_float4(acc[4],  acc[5],  acc[6],  acc[7]);
        *reinterpret_cast<float4*>(pr + 8)  = make_float4(acc[8],  acc[9],  acc[10], acc[11]);
        *reinterpret_cast<float4*>(pr + 12) = make_float4(acc[12], acc[13], acc[14], acc[15]);
    }
    __syncthreads();
    {
        const int rr = tid >> 4, cc = (tid & 15) * 4;
        const float* p0r = smem + 0 * (64 * PS) + rr * PS + cc;
        const float* p1r = smem + 1 * (64 * PS) + rr * PS + cc;
        const float* p2r = smem + 2 * (64 * PS) + rr * PS + cc;
        const float* p3r = smem + 3 * (64 * PS) + rr * PS + cc;
        float4 pa       = *reinterpret_cast<const float4*>(p0r);
        const float4 pb = *reinterpret_cast<const float4*>(p1r);
        const float4 pc = *reinterpret_cast<const float4*>(p2r);
        const float4 pd4 = *reinterpret_cast<const float4*>(p3r);
        pa.x += pb.x + pc.x + pd4.x;
        pa.y += pb.y + pc.y + pd4.y;
        pa.z += pb.z + pc.z + pd4.z;
        pa.w += pb.w + pc.w + pd4.w;
        float* __restrict__ pd = kc ? p1 : (out + OFF_COMBINE);
        *reinterpret_cast<float4*>(pd + (size_t)(tile * 64 + rr) * NEXP + cc) = pa;
    }
}

// K2: logits = p0 + p1 + noise; top-2 + renormalized gates; all outputs.
__global__ __launch_bounds__(1024)
void finish_kernel(const float* __restrict__ p1,
                   const float* __restrict__ noise,
                   float* __restrict__ out) {
    __shared__ float lg[64][PS];
    __shared__ float g1s[64], g2s[64];
    __shared__ int   i1s[64], i2s[64];
    __shared__ float bins[NEXP];

    const int tid = threadIdx.x;
    const int r = tid >> 4, c = (tid & 15) * 4;
    const size_t rowbase = (size_t)(blockIdx.x * 64 + r) * NEXP + c;

    float4 a       = *reinterpret_cast<const float4*>(out + OFF_COMBINE + rowbase);
    const float4 b = *reinterpret_cast<const float4*>(p1 + rowbase);
    const float4 n = *reinterpret_cast<const float4*>(noise + rowbase);
    a.x += b.x + n.x; a.y += b.y + n.y; a.z += b.z + n.z; a.w += b.w + n.w;
    *reinterpret_cast<float4*>(&lg[r][c]) = a;
    if (tid < NEXP) bins[tid] = 0.0f;
    __syncthreads();

    if (tid < 64) {   // wave 0, lane = row
        const int rr = tid;
        float m1 = -1e30f, m2 = -1e30f;
        int i1 = 0, i2 = 0;
        #pragma unroll
        for (int j = 0; j < NEXP; j += 4) {
            const float4 s = *reinterpret_cast<const float4*>(&lg[rr][j]);
            if (s.x > m1) { m2 = m1; i2 = i1; m1 = s.x; i1 = j + 0; } else if (s.x > m2) { m2 = s.x; i2 = j + 0; }
            if (s.y > m1) { m2 = m1; i2 = i1; m1 = s.y; i1 = j + 1; } else if (s.y > m2) { m2 = s.y; i2 = j + 1; }
            if (s.z > m1) { m2 = m1; i2 = i1; m1 = s.z; i1 = j + 2; } else if (s.z > m2) { m2 = s.z; i2 = j + 2; }
            if (s.w > m1) { m2 = m1; i2 = i1; m1 = s.w; i1 = j + 3; } else if (s.w > m2) { m2 = s.w; i2 = j + 3; }
        }
        // Softmax Z cancels under top-2 renorm: g1 = 1/(1+exp(l2-l1)).
        const float t  = expf(m2 - m1);
        const float g1 = 1.0f / (1.0f + t);
        const float g2 = 1.0f - g1;

        const int row = blockIdx.x * 64 + rr;
        out[OFF_IDX + row * 2 + 0]   = (float)i1;
        out[OFF_IDX + row * 2 + 1]   = (float)i2;
        out[OFF_GATES + row * 2 + 0] = g1;
        out[OFF_GATES + row * 2 + 1] = g2;

        g1s[rr] = g1; g2s[rr] = g2; i1s[rr] = i1; i2s[rr] = i2;
        atomicAdd(&bins[i1], 1.0f);
        atomicAdd(&bins[i2], 1.0f);
    }
    __syncthreads();

    {
        const int   ia = i1s[r], ib = i2s[r];
        const float ga = g1s[r], gb = g2s[r];
        float4 v;
        v.x = (c + 0 == ia) ? ga : (c + 0 == ib) ? gb : 0.0f;
        v.y = (c + 1 == ia) ? ga : (c + 1 == ib) ? gb : 0.0f;
        v.z = (c + 2 == ia) ? ga : (c + 2 == ib) ? gb : 0.0f;
        v.w = (c + 3 == ia) ? ga : (c + 3 == ib) ? gb : 0.0f;
        *reinterpret_cast<float4*>(out + OFF_COMBINE + rowbase) = v;
    }

    if (tid < NEXP) {
        const float v = bins[tid];
        if (v != 0.0f) atomicAdd(out + OFF_ACT + tid, v);
    }
}

extern "C" void kernel_launch(void* const* d_in, const int* in_sizes, int n_in,
                              void* d_out, int out_size, void* d_ws, size_t ws_size,
                              hipStream_t stream) {
    const float* x     = (const float*)d_in[0];
    const float* wg    = (const float*)d_in[1];
    const float* noise = (const float*)d_in[2];
    float* out = (float*)d_out;
    float* p1  = (float*)d_ws;   // 4 MB scratch for the kc=1 K-partial

    gemm_kernel<<<512, 1024, 0, stream>>>(x, wg, out, p1);
    finish_kernel<<<T_TOKENS / 64, 1024, 0, stream>>>(p1, noise, out);
}